// Round 3
// baseline (116.163 us; speedup 1.0000x reference)
//
#include <hip/hip_runtime.h>

#define B 64
#define S 512
#define D 768
#define E 32
#define N_ENT (B * E)        // 2048
#define MPE 4
#define M (N_ENT * MPE)      // 8192
#define N_TYPES 6
#define P (B * E * (E - 1))  // 63488

#define D4 (D / 4)                     // 192 float4 slots per row
#define LSE_BLOCKS (N_ENT * D4 / 256)  // 1536
#define TYPES_ELEMS (P * N_TYPES)      // 380928
#define TYPES_BLOCKS ((TYPES_ELEMS + 255) / 256) // 1488
#define CLS_BASE (LSE_BLOCKS + TYPES_BLOCKS)     // 3024
#define CLS_GRID 2048
#define CLS_SLOTS (P * D4)             // 12,189,696 float4 slots (row 0)
#define HT_SLOTS (P * 2 * D4)          // 24,379,392 float4 slots (rows 1,2)

typedef float f32x4 __attribute__((ext_vector_type(4)));

__device__ __forceinline__ float lse4(float a, float b, float c, float d) {
    float mx = fmaxf(fmaxf(a, b), fmaxf(c, d));
    return logf(expf(a - mx) + expf(b - mx) + expf(c - mx) + expf(d - mx)) + mx;
}

// ---------------------------------------------------------------------------
// Launch 1 — three independent jobs in one dispatch so the latency-bound LSE
// gathers overlap with write-bound streaming:
//  blocks [0, LSE_BLOCKS):      per-(entity,d4) logsumexp -> ent[] in d_ws
//  blocks [LSE, LSE+TYPES):     pair_types one-hot sums
//  blocks [CLS_BASE, +CLS_GRID): grid-stride cls-row writes (out row 0) —
//                               depends only on hidden[:,0], not on ent.
// ---------------------------------------------------------------------------
__global__ __launch_bounds__(256) void prep_cls_kernel(
    const float* __restrict__ hidden,
    const int* __restrict__ mention_entity,
    const int* __restrict__ mention_pos,
    const int* __restrict__ pair_head,
    const int* __restrict__ pair_tail,
    const int* __restrict__ pair_doc,
    const int* __restrict__ ent_type,
    float* __restrict__ ent,
    float* __restrict__ out_feat,
    float* __restrict__ out_types) {
    const unsigned b = blockIdx.x;
    const unsigned t = threadIdx.x;

    if (b < LSE_BLOCKS) {
        const unsigned idx = b * 256u + t;          // over N_ENT * D4
        const unsigned e = idx / D4;
        const unsigned d4 = idx - e * D4;
        const int doc = mention_entity[e * MPE] / E;
        const float* rowbase = hidden + (size_t)doc * S * D + (size_t)d4 * 4;

        f32x4 x[MPE];
#pragma unroll
        for (int m = 0; m < MPE; ++m) {
            const int pos = mention_pos[e * MPE + m] + 1;
            x[m] = *(const f32x4*)(rowbase + (size_t)pos * D);
        }
        f32x4 o;
        o.x = lse4(x[0].x, x[1].x, x[2].x, x[3].x);
        o.y = lse4(x[0].y, x[1].y, x[2].y, x[3].y);
        o.z = lse4(x[0].z, x[1].z, x[2].z, x[3].z);
        o.w = lse4(x[0].w, x[1].w, x[2].w, x[3].w);
        *(f32x4*)(ent + (size_t)e * D + (size_t)d4 * 4) = o;
    } else if (b < CLS_BASE) {
        const unsigned i = (b - LSE_BLOCKS) * 256u + t;  // over P * N_TYPES
        if (i < TYPES_ELEMS) {
            const unsigned p = i / N_TYPES;
            const int ty = (int)(i - p * N_TYPES);
            const int th = ent_type[pair_head[p]];
            const int tt = ent_type[pair_tail[p]];
            out_types[i] = (float)((ty == th) + (ty == tt));
        }
    } else {
        // cls rows: out_feat[p][0][:] = hidden[pair_doc[p]][0][:]
        f32x4* out4 = (f32x4*)out_feat;
        const unsigned stride = CLS_GRID * 256u;
        for (unsigned idx = (b - CLS_BASE) * 256u + t; idx < (unsigned)CLS_SLOTS;
             idx += stride) {
            const unsigned p = idx / D4;            // wave-uniform (D4 = 3*64)
            const unsigned d4 = idx - p * D4;
            const f32x4* src = (const f32x4*)(hidden + (size_t)pair_doc[p] * (S * D));
            __builtin_nontemporal_store(src[d4], &out4[(size_t)p * (3 * D4) + d4]);
        }
    }
}

// ---------------------------------------------------------------------------
// Launch 2 — head/tail rows (out rows 1,2), grid-stride, wave-uniform p/r,
// broadcast index loads, L2/L3-hit ent reads, streaming nontemporal stores.
// ---------------------------------------------------------------------------
__global__ __launch_bounds__(256) void ht_kernel(
    const int* __restrict__ pair_head,
    const int* __restrict__ pair_tail,
    const float* __restrict__ ent,
    f32x4* __restrict__ out4) {
    const unsigned stride = gridDim.x * blockDim.x;
    for (unsigned idx = blockIdx.x * blockDim.x + threadIdx.x;
         idx < (unsigned)HT_SLOTS; idx += stride) {
        const unsigned p = idx / (2 * D4);          // magic mul
        const unsigned rem = idx - p * (2 * D4);
        const unsigned r = rem / D4;                // 0=head, 1=tail (wave-uniform)
        const unsigned d4 = rem - r * D4;
        const int q = (r == 0) ? pair_head[p] : pair_tail[p];
        const f32x4* src = (const f32x4*)(ent + (size_t)q * D);
        __builtin_nontemporal_store(
            src[d4], &out4[(size_t)p * (3 * D4) + (size_t)(r + 1) * D4 + d4]);
    }
}

extern "C" void kernel_launch(void* const* d_in, const int* in_sizes, int n_in,
                              void* d_out, int out_size, void* d_ws, size_t ws_size,
                              hipStream_t stream) {
    const float* hidden       = (const float*)d_in[0];
    const int* mention_entity = (const int*)d_in[1];
    const int* mention_pos    = (const int*)d_in[2];
    const int* pair_head      = (const int*)d_in[3];
    const int* pair_tail      = (const int*)d_in[4];
    const int* pair_doc       = (const int*)d_in[5];
    const int* ent_type       = (const int*)d_in[6];

    float* out       = (float*)d_out;
    float* out_feat  = out;                      // P*3*D floats
    float* out_types = out + (size_t)P * 3 * D;  // P*N_TYPES floats

    float* ent = (float*)d_ws;                   // N_ENT*D floats = 6.3 MB

    prep_cls_kernel<<<CLS_BASE + CLS_GRID, 256, 0, stream>>>(
        hidden, mention_entity, mention_pos, pair_head, pair_tail, pair_doc,
        ent_type, ent, out_feat, out_types);

    ht_kernel<<<2048, 256, 0, stream>>>(
        pair_head, pair_tail, ent, (f32x4*)out_feat);
}